// Round 1
// baseline (205.186 us; speedup 1.0000x reference)
//
#include <hip/hip_runtime.h>

#define L_LEN 61440
#define NBATCH 512
#define EMAX 128
#define MAXRUNS 1024
#define NWORDS 960          // L_LEN / 64
#define WPT 4               // words per thread; threads 0..239 active
#define NTHREADS 256
#define NITER 240           // L_LEN / NTHREADS
#define IOU_THRESH 0.2f
#define LEN_THRESH 128

__device__ __forceinline__ float iou_val(const int* s_o, const int* e_o,
                                         const int* s_t, const int* e_t,
                                         int i, int j) {
    int so = s_o[i], eo = e_o[i], st = s_t[j], et = e_t[j];
    int lo = eo < et ? eo : et;
    int hi = so > st ? so : st;
    int inter = lo - hi;
    if (inter < 0) inter = 0;
    int den = (eo - so) + (et - st) - inter;
    if (den < 1) den = 1;
    return (float)inter / (float)den;
}

__global__ __launch_bounds__(NTHREADS) void event_f1_kernel(
        const float* __restrict__ outp, const float* __restrict__ tgtp,
        int* __restrict__ counters) {
    __shared__ unsigned long long bm[NWORDS];
    __shared__ int cnt_s[NTHREADS], cnt_e[NTHREADS];
    __shared__ int runs_s[MAXRUNS], runs_e[MAXRUNS];
    __shared__ int s_o[EMAX], e_o[EMAX], s_t[EMAX], e_t[EMAX];
    __shared__ int sh_total;
    __shared__ int n_out_s, n_tgt_s;
    __shared__ float maxr[EMAX], maxc[EMAX];
    __shared__ int idxr[EMAX], idxc[EMAX];
    __shared__ unsigned char mutr[EMAX], mutc[EMAX], rone[EMAX], cone[EMAX];
    __shared__ int idxr1[EMAX], idxc1[EMAX];
    __shared__ unsigned char mutr1[EMAX], mutc1[EMAX], rone1[EMAX], cone1[EMAX];
    __shared__ int tp_sh;

    const int tid = threadIdx.x;
    const int row = blockIdx.x;

    // ---- phase 0: output events (with short-run filter); phase 1: target ----
    for (int phase = 0; phase < 2; ++phase) {
        const float* rowp = (phase == 0 ? outp : tgtp) + (size_t)row * L_LEN;

        // 1) build LDS bitmask via per-wave ballot (coalesced global reads)
        for (int it = 0; it < NITER; ++it) {
            float v = rowp[it * NTHREADS + tid];
            bool b = (phase == 0) ? (v >= 0.5f) : (v != 0.0f);
            unsigned long long m = __ballot(b);
            if ((tid & 63) == 0) bm[it * 4 + (tid >> 6)] = m;
        }
        __syncthreads();

        // 2) count run starts/ends per thread (contiguous WPT words each)
        int cs = 0, ce = 0;
        if (tid < NWORDS / WPT) {
            for (int k = 0; k < WPT; ++k) {
                int w = tid * WPT + k;
                unsigned long long b = bm[w];
                unsigned long long prev = (w > 0) ? (bm[w - 1] >> 63) : 0ULL;
                unsigned long long nxt  = (w < NWORDS - 1) ? (bm[w + 1] & 1ULL) : 0ULL;
                unsigned long long sw = b & ~((b << 1) | prev);
                unsigned long long ew = b & ~((b >> 1) | (nxt << 63));
                cs += __popcll(sw);
                ce += __popcll(ew);
            }
        }
        cnt_s[tid] = cs;
        cnt_e[tid] = ce;
        __syncthreads();

        // 3) exclusive scan (serial, tiny)
        if (tid == 0) {
            int as = 0, ae = 0;
            for (int t = 0; t < NTHREADS; ++t) {
                int s0 = cnt_s[t]; cnt_s[t] = as; as += s0;
                int e0 = cnt_e[t]; cnt_e[t] = ae; ae += e0;
            }
            sh_total = as;   // number of runs (== number of ends)
        }
        __syncthreads();

        // 4) ordered extraction of run starts / ends
        if (tid < NWORDS / WPT) {
            int is = cnt_s[tid], ie = cnt_e[tid];
            for (int k = 0; k < WPT; ++k) {
                int w = tid * WPT + k;
                unsigned long long b = bm[w];
                unsigned long long prev = (w > 0) ? (bm[w - 1] >> 63) : 0ULL;
                unsigned long long nxt  = (w < NWORDS - 1) ? (bm[w + 1] & 1ULL) : 0ULL;
                unsigned long long sw = b & ~((b << 1) | prev);
                unsigned long long ew = b & ~((b >> 1) | (nxt << 63));
                while (sw) {
                    int kk = __builtin_ctzll(sw);
                    if (is < MAXRUNS) runs_s[is] = w * 64 + kk;
                    ++is;
                    sw &= sw - 1;
                }
                while (ew) {
                    int kk = __builtin_ctzll(ew);
                    if (ie < MAXRUNS) runs_e[ie] = w * 64 + kk + 1;
                    ++ie;
                    ew &= ew - 1;
                }
            }
        }
        __syncthreads();

        // 5) filter (output) / copy (target), pad to EMAX with [L, L]
        if (tid == 0) {
            int n = sh_total;
            int lim = n < MAXRUNS ? n : MAXRUNS;
            if (phase == 0) {
                int m = 0;
                for (int k = 0; k < lim; ++k) {
                    int len = runs_e[k] - runs_s[k];
                    if (len >= LEN_THRESH) {
                        if (m < EMAX) { s_o[m] = runs_s[k]; e_o[m] = runs_e[k]; }
                        ++m;
                    }
                }
                int mc = m < EMAX ? m : EMAX;
                for (int k = mc; k < EMAX; ++k) { s_o[k] = L_LEN; e_o[k] = L_LEN; }
                n_out_s = m;
            } else {
                int mc = lim < EMAX ? lim : EMAX;
                for (int k = 0; k < mc; ++k) { s_t[k] = runs_s[k]; e_t[k] = runs_e[k]; }
                for (int k = mc; k < EMAX; ++k) { s_t[k] = L_LEN; e_t[k] = L_LEN; }
                n_tgt_s = n;
            }
        }
        __syncthreads();
    }

    // ---- matching: two passes of mutual best-match ----
    if (tid == 0) tp_sh = 0;
    __syncthreads();

    for (int pass = 0; pass < 2; ++pass) {
        if (tid < EMAX) {
            int i = tid;
            float best = -2.0f; int bi = 0;
            for (int j = 0; j < EMAX; ++j) {
                float v;
                if (pass == 0) {
                    v = iou_val(s_o, e_o, s_t, e_t, i, j);
                } else {
                    bool om = (((j == idxr1[i]) && rone1[i]) ||
                               ((i == idxc1[j]) && cone1[j])) &&
                              !mutr1[i] && !mutc1[j];
                    v = om ? iou_val(s_o, e_o, s_t, e_t, i, j) : -1.0f;
                }
                if (v > best) { best = v; bi = j; }   // first-occurrence argmax
            }
            maxr[i] = best; idxr[i] = bi;
        } else {
            int j = tid - EMAX;
            float best = -2.0f; int bi = 0;
            for (int i = 0; i < EMAX; ++i) {
                float v;
                if (pass == 0) {
                    v = iou_val(s_o, e_o, s_t, e_t, i, j);
                } else {
                    bool om = (((j == idxr1[i]) && rone1[i]) ||
                               ((i == idxc1[j]) && cone1[j])) &&
                              !mutr1[i] && !mutc1[j];
                    v = om ? iou_val(s_o, e_o, s_t, e_t, i, j) : -1.0f;
                }
                if (v > best) { best = v; bi = i; }
            }
            maxc[j] = best; idxc[j] = bi;
        }
        __syncthreads();

        if (tid < EMAX) {
            int i = tid;
            bool mr = (idxc[idxr[i]] == i) && (maxr[i] >= IOU_THRESH);
            mutr[i] = mr;
            rone[i] = (!mr) && (maxr[i] >= IOU_THRESH);
        } else {
            int j = tid - EMAX;
            bool mc = (idxr[idxc[j]] == j) && (maxc[j] >= IOU_THRESH);
            mutc[j] = mc;
            cone[j] = (!mc) && (maxc[j] >= IOU_THRESH);
        }
        __syncthreads();

        if (pass == 0 && tid < EMAX) {
            idxr1[tid] = idxr[tid]; mutr1[tid] = mutr[tid]; rone1[tid] = rone[tid];
            idxc1[tid] = idxc[tid]; mutc1[tid] = mutc[tid]; cone1[tid] = cone[tid];
        }
        __syncthreads();

        if (tid == 0) {
            int tp = 0;
            for (int i = 0; i < EMAX; ++i) tp += mutr[i];
            tp_sh += tp;
        }
        __syncthreads();
    }

    // ---- per-batch TP/FN/FP with empty-case rules, global accumulate ----
    if (tid == 0) {
        int n_out = n_out_s, n_tgt = n_tgt_s, tp = tp_sh;
        int tpb, fnb, fpb;
        if (n_tgt == 0)       { tpb = 0;  fnb = n_out; fpb = 0; }
        else if (n_out == 0)  { tpb = 0;  fnb = 0;     fpb = n_tgt; }
        else                  { tpb = tp; fnb = n_tgt - tp; fpb = n_out - tp; }
        atomicAdd(&counters[0], tpb);
        atomicAdd(&counters[1], fnb);
        atomicAdd(&counters[2], fpb);
    }
}

__global__ void zero_counters(int* c) {
    if (threadIdx.x < 3) c[threadIdx.x] = 0;
}

__global__ void finalize_kernel(const int* __restrict__ c, float* __restrict__ out) {
    float TP = (float)c[0], FN = (float)c[1], FP = (float)c[2];
    float rd = TP + FN;
    float recall = (rd == 0.0f) ? 0.0f : TP / fmaxf(rd, 1.0f);
    float pd = TP + FP;
    float precision = (pd == 0.0f) ? 0.0f : TP / fmaxf(pd, 1.0f);
    float s = precision + recall;
    float f1 = (s == 0.0f) ? 0.0f : 2.0f * precision * recall / fmaxf(s, 1e-30f);
    out[0] = recall; out[1] = precision; out[2] = f1;
}

extern "C" void kernel_launch(void* const* d_in, const int* in_sizes, int n_in,
                              void* d_out, int out_size, void* d_ws, size_t ws_size,
                              hipStream_t stream) {
    const float* outp = (const float*)d_in[0];
    const float* tgtp = (const float*)d_in[1];
    float* res = (float*)d_out;
    int* counters = (int*)d_ws;

    zero_counters<<<1, 64, 0, stream>>>(counters);
    event_f1_kernel<<<NBATCH, NTHREADS, 0, stream>>>(outp, tgtp, counters);
    finalize_kernel<<<1, 1, 0, stream>>>(counters, res);
}

// Round 2
// 98.087 us; speedup vs baseline: 2.0919x; 2.0919x over previous
//
#include <hip/hip_runtime.h>

typedef unsigned long long ull;

#define L_LEN 61440
#define NBATCH 512
#define EMAX 128
#define RUNBUF 512          // max buffered runs per signal (dataset max ~120)
#define NWORDS 960          // L_LEN / 64
#define NTHREADS 256
#define CHUNK_ITERS 60      // L_LEN / 1024 (4 waves x 256 elements)
#define IOU_THRESH 0.2f
#define LEN_THRESH 128

__global__ __launch_bounds__(NTHREADS) void event_f1_kernel(
        const float* __restrict__ outp, const float* __restrict__ tgtp,
        int* __restrict__ counters) {
    __shared__ ull bm[2][NWORDS];                 // [0]=output, [1]=target
    __shared__ int runs_s[2][RUNBUF], runs_e[2][RUNBUF];
    __shared__ int wtot_s[4], wtot_e[4];
    __shared__ int s_o[EMAX], e_o[EMAX], s_t[EMAX], e_t[EMAX];
    __shared__ int n_out_s, n_tgt_s;
    __shared__ int idxr[EMAX], idxc[EMAX];
    __shared__ int idxr1[EMAX], idxc1[EMAX];
    __shared__ int rone1[EMAX], cone1[EMAX], mutr1[EMAX], mutc1[EMAX];
    __shared__ int tp_sh;

    const int tid = threadIdx.x;
    const int row = blockIdx.x;
    const int lane = tid & 63;
    const int wid = tid >> 6;

    const float* op = outp + (size_t)row * L_LEN;
    const float* tg = tgtp + (size_t)row * L_LEN;

    if (tid == 0) tp_sh = 0;

    // ---- 1) build both bitmasks: 8 independent dword loads / thread / iter ----
    #pragma unroll 2
    for (int it = 0; it < CHUNK_ITERS; ++it) {
        int base = it * 1024 + wid * 256 + lane;
        float o0 = op[base];       float o1 = op[base + 64];
        float o2 = op[base + 128]; float o3 = op[base + 192];
        float t0 = tg[base];       float t1 = tg[base + 64];
        float t2 = tg[base + 128]; float t3 = tg[base + 192];
        ull mo0 = __ballot(o0 >= 0.5f); ull mo1 = __ballot(o1 >= 0.5f);
        ull mo2 = __ballot(o2 >= 0.5f); ull mo3 = __ballot(o3 >= 0.5f);
        ull mt0 = __ballot(t0 != 0.0f); ull mt1 = __ballot(t1 != 0.0f);
        ull mt2 = __ballot(t2 != 0.0f); ull mt3 = __ballot(t3 != 0.0f);
        if (lane == 0) {
            int wb = it * 16 + wid * 4;
            bm[0][wb] = mo0; bm[0][wb + 1] = mo1; bm[0][wb + 2] = mo2; bm[0][wb + 3] = mo3;
            bm[1][wb] = mt0; bm[1][wb + 1] = mt1; bm[1][wb + 2] = mt2; bm[1][wb + 3] = mt3;
        }
    }
    __syncthreads();

    // ---- 2) run extraction: threads 0-127 -> output, 128-255 -> target ----
    const int group = tid >> 7;        // 0 = output, 1 = target
    const int gtid = tid & 127;
    const ull* bmg = bm[group];
    const int w0 = gtid * 8;           // 8 words per thread; gtid>=120 idle

    int cs = 0, ce = 0;
    #pragma unroll
    for (int k = 0; k < 8; ++k) {
        int w = w0 + k;
        if (w < NWORDS) {
            ull b = bmg[w];
            ull prev = (w > 0) ? (bmg[w - 1] >> 63) : 0ull;
            ull nxt  = (w < NWORDS - 1) ? (bmg[w + 1] & 1ull) : 0ull;
            ull swd = b & ~((b << 1) | prev);
            ull ewd = b & ~((b >> 1) | (nxt << 63));
            cs += __popcll(swd);
            ce += __popcll(ewd);
        }
    }
    // wave-local inclusive scan (64 lanes)
    int incl_s = cs, incl_e = ce;
    #pragma unroll
    for (int d = 1; d < 64; d <<= 1) {
        int us = __shfl_up(incl_s, d, 64);
        int ue = __shfl_up(incl_e, d, 64);
        if (lane >= d) { incl_s += us; incl_e += ue; }
    }
    if (lane == 63) { wtot_s[wid] = incl_s; wtot_e[wid] = incl_e; }
    __syncthreads();
    int off_s = incl_s - cs, off_e = incl_e - ce;
    if (wid & 1) { off_s += wtot_s[wid & 2]; off_e += wtot_e[wid & 2]; }

    // ordered extraction
    #pragma unroll
    for (int k = 0; k < 8; ++k) {
        int w = w0 + k;
        if (w < NWORDS) {
            ull b = bmg[w];
            ull prev = (w > 0) ? (bmg[w - 1] >> 63) : 0ull;
            ull nxt  = (w < NWORDS - 1) ? (bmg[w + 1] & 1ull) : 0ull;
            ull swd = b & ~((b << 1) | prev);
            ull ewd = b & ~((b >> 1) | (nxt << 63));
            while (swd) {
                int kk = __builtin_ctzll(swd);
                if (off_s < RUNBUF) runs_s[group][off_s] = w * 64 + kk;
                ++off_s;
                swd &= swd - 1;
            }
            while (ewd) {
                int kk = __builtin_ctzll(ewd);
                if (off_e < RUNBUF) runs_e[group][off_e] = w * 64 + kk + 1;
                ++off_e;
                ewd &= ewd - 1;
            }
        }
    }
    __syncthreads();

    const int n_runs_o = wtot_s[0] + wtot_s[1];
    const int n_runs_t = wtot_s[2] + wtot_s[3];

    // ---- 3) filter output runs (serial, ~60 iters); copy target (parallel) ----
    if (tid == 0) {
        int lim = n_runs_o < RUNBUF ? n_runs_o : RUNBUF;
        int m = 0;
        for (int k = 0; k < lim; ++k) {
            int s = runs_s[0][k], e = runs_e[0][k];
            if (e - s >= LEN_THRESH) {
                if (m < EMAX) { s_o[m] = s; e_o[m] = e; }
                ++m;
            }
        }
        for (int k = (m < EMAX ? m : EMAX); k < EMAX; ++k) { s_o[k] = L_LEN; e_o[k] = L_LEN; }
        n_out_s = m;
    }
    if (tid >= 128) {
        int k = tid - 128;
        int mc = n_runs_t < RUNBUF ? n_runs_t : RUNBUF;
        if (mc > EMAX) mc = EMAX;
        if (k < mc) { s_t[k] = runs_s[1][k]; e_t[k] = runs_e[1][k]; }
        else        { s_t[k] = L_LEN;        e_t[k] = L_LEN; }
        if (k == 0) n_tgt_s = n_runs_t;
    }
    __syncthreads();

    // ---- 4) matching: two passes, broadcast-only LDS reads in inner loops ----
    int my_s, my_e;
    if (tid < EMAX) { my_s = s_o[tid]; my_e = e_o[tid]; }
    else            { my_s = s_t[tid - EMAX]; my_e = e_t[tid - EMAX]; }
    const int my_len = my_e - my_s;

    for (int pass = 0; pass < 2; ++pass) {
        float best = -2.0f;
        int bi = 0;
        if (tid < EMAX) {
            const int i = tid;
            int ir1 = 0, r1 = 0, m1 = 0;
            if (pass) { ir1 = idxr1[i]; r1 = rone1[i]; m1 = mutr1[i]; }
            for (int j = 0; j < EMAX; ++j) {
                int st = s_t[j], et = e_t[j];
                int lo = my_e < et ? my_e : et;
                int hi = my_s > st ? my_s : st;
                int inter = lo - hi; if (inter < 0) inter = 0;
                int den = my_len + (et - st) - inter; if (den < 1) den = 1;
                float v = (float)inter / (float)den;
                if (pass) {
                    bool om = (((j == ir1) && r1) || ((i == idxc1[j]) && cone1[j]))
                              && !m1 && !mutc1[j];
                    v = om ? v : -1.0f;
                }
                if (v > best) { best = v; bi = j; }   // first-occurrence argmax
            }
            idxr[i] = bi;
        } else {
            const int j = tid - EMAX;
            int ic1 = 0, c1 = 0, m1 = 0;
            if (pass) { ic1 = idxc1[j]; c1 = cone1[j]; m1 = mutc1[j]; }
            for (int i = 0; i < EMAX; ++i) {
                int so = s_o[i], eo = e_o[i];
                int lo = eo < my_e ? eo : my_e;
                int hi = so > my_s ? so : my_s;
                int inter = lo - hi; if (inter < 0) inter = 0;
                int den = (eo - so) + my_len - inter; if (den < 1) den = 1;
                float v = (float)inter / (float)den;
                if (pass) {
                    bool om = (((j == idxr1[i]) && rone1[i]) || ((i == ic1) && c1))
                              && !mutr1[i] && !m1;
                    v = om ? v : -1.0f;
                }
                if (v > best) { best = v; bi = i; }
            }
            idxc[j] = bi;
        }
        __syncthreads();

        bool mm;
        if (tid < EMAX) mm = (idxc[bi] == tid)          && (best >= IOU_THRESH);
        else            mm = (idxr[bi] == (tid - EMAX)) && (best >= IOU_THRESH);

        if (tid < EMAX) {   // count TP over rows (waves 0,1)
            ull bb = __ballot(mm);
            if (lane == 0) atomicAdd(&tp_sh, (int)__popcll(bb));
        }
        __syncthreads();

        if (pass == 0) {
            if (tid < EMAX) {
                idxr1[tid] = bi;
                mutr1[tid] = mm;
                rone1[tid] = (!mm) && (best >= IOU_THRESH);
            } else {
                idxc1[tid - EMAX] = bi;
                mutc1[tid - EMAX] = mm;
                cone1[tid - EMAX] = (!mm) && (best >= IOU_THRESH);
            }
            __syncthreads();
        }
    }
    __syncthreads();

    // ---- 5) per-batch TP/FN/FP with empty-case rules ----
    if (tid == 0) {
        int n_out = n_out_s, n_tgt = n_tgt_s, tp = tp_sh;
        int tpb, fnb, fpb;
        if (n_tgt == 0)      { tpb = 0;  fnb = n_out;      fpb = 0; }
        else if (n_out == 0) { tpb = 0;  fnb = 0;          fpb = n_tgt; }
        else                 { tpb = tp; fnb = n_tgt - tp; fpb = n_out - tp; }
        atomicAdd(&counters[0], tpb);
        atomicAdd(&counters[1], fnb);
        atomicAdd(&counters[2], fpb);
    }
}

__global__ void zero_counters(int* c) {
    if (threadIdx.x < 3) c[threadIdx.x] = 0;
}

__global__ void finalize_kernel(const int* __restrict__ c, float* __restrict__ out) {
    float TP = (float)c[0], FN = (float)c[1], FP = (float)c[2];
    float rd = TP + FN;
    float recall = (rd == 0.0f) ? 0.0f : TP / fmaxf(rd, 1.0f);
    float pd = TP + FP;
    float precision = (pd == 0.0f) ? 0.0f : TP / fmaxf(pd, 1.0f);
    float s = precision + recall;
    float f1 = (s == 0.0f) ? 0.0f : 2.0f * precision * recall / fmaxf(s, 1e-30f);
    out[0] = recall; out[1] = precision; out[2] = f1;
}

extern "C" void kernel_launch(void* const* d_in, const int* in_sizes, int n_in,
                              void* d_out, int out_size, void* d_ws, size_t ws_size,
                              hipStream_t stream) {
    const float* outp = (const float*)d_in[0];
    const float* tgtp = (const float*)d_in[1];
    float* res = (float*)d_out;
    int* counters = (int*)d_ws;

    zero_counters<<<1, 64, 0, stream>>>(counters);
    event_f1_kernel<<<NBATCH, NTHREADS, 0, stream>>>(outp, tgtp, counters);
    finalize_kernel<<<1, 1, 0, stream>>>(counters, res);
}

// Round 3
// 95.762 us; speedup vs baseline: 2.1427x; 1.0243x over previous
//
#include <hip/hip_runtime.h>

typedef unsigned long long ull;

#define L_LEN 61440
#define NBATCH 512
#define EMAX 128
#define RUNBUF 512          // max buffered runs per signal (dataset max ~120)
#define NWORDS 960          // L_LEN / 64
#define NTHREADS 256
#define NITER 15            // L_LEN / (NTHREADS*16)
#define IOU_THRESH 0.2f
#define LEN_THRESH 128

__device__ __forceinline__ unsigned int mask16_ge(float4 a, float4 b, float4 c, float4 d, float thr) {
    unsigned int m = 0;
    m |= (a.x >= thr) ? 0x0001u : 0u; m |= (a.y >= thr) ? 0x0002u : 0u;
    m |= (a.z >= thr) ? 0x0004u : 0u; m |= (a.w >= thr) ? 0x0008u : 0u;
    m |= (b.x >= thr) ? 0x0010u : 0u; m |= (b.y >= thr) ? 0x0020u : 0u;
    m |= (b.z >= thr) ? 0x0040u : 0u; m |= (b.w >= thr) ? 0x0080u : 0u;
    m |= (c.x >= thr) ? 0x0100u : 0u; m |= (c.y >= thr) ? 0x0200u : 0u;
    m |= (c.z >= thr) ? 0x0400u : 0u; m |= (c.w >= thr) ? 0x0800u : 0u;
    m |= (d.x >= thr) ? 0x1000u : 0u; m |= (d.y >= thr) ? 0x2000u : 0u;
    m |= (d.z >= thr) ? 0x4000u : 0u; m |= (d.w >= thr) ? 0x8000u : 0u;
    return m;
}

__device__ __forceinline__ unsigned int mask16_ne0(float4 a, float4 b, float4 c, float4 d) {
    unsigned int m = 0;
    m |= (a.x != 0.0f) ? 0x0001u : 0u; m |= (a.y != 0.0f) ? 0x0002u : 0u;
    m |= (a.z != 0.0f) ? 0x0004u : 0u; m |= (a.w != 0.0f) ? 0x0008u : 0u;
    m |= (b.x != 0.0f) ? 0x0010u : 0u; m |= (b.y != 0.0f) ? 0x0020u : 0u;
    m |= (b.z != 0.0f) ? 0x0040u : 0u; m |= (b.w != 0.0f) ? 0x0080u : 0u;
    m |= (c.x != 0.0f) ? 0x0100u : 0u; m |= (c.y != 0.0f) ? 0x0200u : 0u;
    m |= (c.z != 0.0f) ? 0x0400u : 0u; m |= (c.w != 0.0f) ? 0x0800u : 0u;
    m |= (d.x != 0.0f) ? 0x1000u : 0u; m |= (d.y != 0.0f) ? 0x2000u : 0u;
    m |= (d.z != 0.0f) ? 0x4000u : 0u; m |= (d.w != 0.0f) ? 0x8000u : 0u;
    return m;
}

__global__ __launch_bounds__(NTHREADS) void event_f1_kernel(
        const float* __restrict__ outp, const float* __restrict__ tgtp,
        int* __restrict__ counters) {
    __shared__ ull bm[2][NWORDS];                 // [0]=output, [1]=target
    __shared__ int runs_s[2][RUNBUF], runs_e[2][RUNBUF];
    __shared__ int wtot_s[4], wtot_e[4];
    __shared__ int s_o[EMAX], e_o[EMAX], s_t[EMAX], e_t[EMAX];
    __shared__ int n_out_s, n_tgt_s;
    __shared__ int idxr[EMAX], idxc[EMAX];
    __shared__ int idxr1[EMAX], idxc1[EMAX];
    __shared__ int rone1[EMAX], cone1[EMAX], mutr1[EMAX], mutc1[EMAX];
    __shared__ int tp_sh;

    const int tid = threadIdx.x;
    const int row = blockIdx.x;
    const int lane = tid & 63;
    const int wid = tid >> 6;

    const float* op = outp + (size_t)row * L_LEN;
    const float* tg = tgtp + (size_t)row * L_LEN;

    if (tid == 0) tp_sh = 0;

    // ---- 1) build both bitmasks: per-thread 16-elem masks from float4 loads ----
    // Thread t covers elements [it*4096 + t*16, +16); writes one ushort per signal.
    // 8 independent 16B loads per thread per iter -> ~8KB/wave in flight.
    unsigned short* bmo16 = (unsigned short*)bm[0];
    unsigned short* bmt16 = (unsigned short*)bm[1];
    #pragma unroll 2
    for (int it = 0; it < NITER; ++it) {
        const float4* po = (const float4*)(op + it * 4096 + tid * 16);
        const float4* pt = (const float4*)(tg + it * 4096 + tid * 16);
        float4 a0 = po[0], a1 = po[1], a2 = po[2], a3 = po[3];
        float4 b0 = pt[0], b1 = pt[1], b2 = pt[2], b3 = pt[3];
        unsigned int mo = mask16_ge(a0, a1, a2, a3, 0.5f);
        unsigned int mt = mask16_ne0(b0, b1, b2, b3);
        bmo16[it * 256 + tid] = (unsigned short)mo;
        bmt16[it * 256 + tid] = (unsigned short)mt;
    }
    __syncthreads();

    // ---- 2) run extraction: threads 0-127 -> output, 128-255 -> target ----
    const int group = tid >> 7;        // 0 = output, 1 = target
    const int gtid = tid & 127;
    const ull* bmg = bm[group];
    const int w0 = gtid * 8;           // 8 words per thread; gtid>=120 idle

    int cs = 0, ce = 0;
    #pragma unroll
    for (int k = 0; k < 8; ++k) {
        int w = w0 + k;
        if (w < NWORDS) {
            ull b = bmg[w];
            ull prev = (w > 0) ? (bmg[w - 1] >> 63) : 0ull;
            ull nxt  = (w < NWORDS - 1) ? (bmg[w + 1] & 1ull) : 0ull;
            ull swd = b & ~((b << 1) | prev);
            ull ewd = b & ~((b >> 1) | (nxt << 63));
            cs += __popcll(swd);
            ce += __popcll(ewd);
        }
    }
    // wave-local inclusive scan (64 lanes)
    int incl_s = cs, incl_e = ce;
    #pragma unroll
    for (int d = 1; d < 64; d <<= 1) {
        int us = __shfl_up(incl_s, d, 64);
        int ue = __shfl_up(incl_e, d, 64);
        if (lane >= d) { incl_s += us; incl_e += ue; }
    }
    if (lane == 63) { wtot_s[wid] = incl_s; wtot_e[wid] = incl_e; }
    __syncthreads();
    int off_s = incl_s - cs, off_e = incl_e - ce;
    if (wid & 1) { off_s += wtot_s[wid & 2]; off_e += wtot_e[wid & 2]; }

    // ordered extraction
    #pragma unroll
    for (int k = 0; k < 8; ++k) {
        int w = w0 + k;
        if (w < NWORDS) {
            ull b = bmg[w];
            ull prev = (w > 0) ? (bmg[w - 1] >> 63) : 0ull;
            ull nxt  = (w < NWORDS - 1) ? (bmg[w + 1] & 1ull) : 0ull;
            ull swd = b & ~((b << 1) | prev);
            ull ewd = b & ~((b >> 1) | (nxt << 63));
            while (swd) {
                int kk = __builtin_ctzll(swd);
                if (off_s < RUNBUF) runs_s[group][off_s] = w * 64 + kk;
                ++off_s;
                swd &= swd - 1;
            }
            while (ewd) {
                int kk = __builtin_ctzll(ewd);
                if (off_e < RUNBUF) runs_e[group][off_e] = w * 64 + kk + 1;
                ++off_e;
                ewd &= ewd - 1;
            }
        }
    }
    __syncthreads();

    const int n_runs_o = wtot_s[0] + wtot_s[1];
    const int n_runs_t = wtot_s[2] + wtot_s[3];

    // ---- 3) filter output runs (serial, ~60 iters); copy target (parallel) ----
    if (tid == 0) {
        int lim = n_runs_o < RUNBUF ? n_runs_o : RUNBUF;
        int m = 0;
        for (int k = 0; k < lim; ++k) {
            int s = runs_s[0][k], e = runs_e[0][k];
            if (e - s >= LEN_THRESH) {
                if (m < EMAX) { s_o[m] = s; e_o[m] = e; }
                ++m;
            }
        }
        for (int k = (m < EMAX ? m : EMAX); k < EMAX; ++k) { s_o[k] = L_LEN; e_o[k] = L_LEN; }
        n_out_s = m;
    }
    if (tid >= 128) {
        int k = tid - 128;
        int mc = n_runs_t < RUNBUF ? n_runs_t : RUNBUF;
        if (mc > EMAX) mc = EMAX;
        if (k < mc) { s_t[k] = runs_s[1][k]; e_t[k] = runs_e[1][k]; }
        else        { s_t[k] = L_LEN;        e_t[k] = L_LEN; }
        if (k == 0) n_tgt_s = n_runs_t;
    }
    __syncthreads();

    // ---- 4) matching: two passes, broadcast-only LDS reads in inner loops ----
    int my_s, my_e;
    if (tid < EMAX) { my_s = s_o[tid]; my_e = e_o[tid]; }
    else            { my_s = s_t[tid - EMAX]; my_e = e_t[tid - EMAX]; }
    const int my_len = my_e - my_s;

    for (int pass = 0; pass < 2; ++pass) {
        float best = -2.0f;
        int bi = 0;
        if (tid < EMAX) {
            const int i = tid;
            int ir1 = 0, r1 = 0, m1 = 0;
            if (pass) { ir1 = idxr1[i]; r1 = rone1[i]; m1 = mutr1[i]; }
            for (int j = 0; j < EMAX; ++j) {
                int st = s_t[j], et = e_t[j];
                int lo = my_e < et ? my_e : et;
                int hi = my_s > st ? my_s : st;
                int inter = lo - hi; if (inter < 0) inter = 0;
                int den = my_len + (et - st) - inter; if (den < 1) den = 1;
                float v = (float)inter / (float)den;
                if (pass) {
                    bool om = (((j == ir1) && r1) || ((i == idxc1[j]) && cone1[j]))
                              && !m1 && !mutc1[j];
                    v = om ? v : -1.0f;
                }
                if (v > best) { best = v; bi = j; }   // first-occurrence argmax
            }
            idxr[i] = bi;
        } else {
            const int j = tid - EMAX;
            int ic1 = 0, c1 = 0, m1 = 0;
            if (pass) { ic1 = idxc1[j]; c1 = cone1[j]; m1 = mutc1[j]; }
            for (int i = 0; i < EMAX; ++i) {
                int so = s_o[i], eo = e_o[i];
                int lo = eo < my_e ? eo : my_e;
                int hi = so > my_s ? so : my_s;
                int inter = lo - hi; if (inter < 0) inter = 0;
                int den = (eo - so) + my_len - inter; if (den < 1) den = 1;
                float v = (float)inter / (float)den;
                if (pass) {
                    bool om = (((j == idxr1[i]) && rone1[i]) || ((i == ic1) && c1))
                              && !mutr1[i] && !m1;
                    v = om ? v : -1.0f;
                }
                if (v > best) { best = v; bi = i; }
            }
            idxc[j] = bi;
        }
        __syncthreads();

        bool mm;
        if (tid < EMAX) mm = (idxc[bi] == tid)          && (best >= IOU_THRESH);
        else            mm = (idxr[bi] == (tid - EMAX)) && (best >= IOU_THRESH);

        if (tid < EMAX) {   // count TP over rows (waves 0,1)
            ull bb = __ballot(mm);
            if (lane == 0) atomicAdd(&tp_sh, (int)__popcll(bb));
        }
        __syncthreads();

        if (pass == 0) {
            if (tid < EMAX) {
                idxr1[tid] = bi;
                mutr1[tid] = mm;
                rone1[tid] = (!mm) && (best >= IOU_THRESH);
            } else {
                idxc1[tid - EMAX] = bi;
                mutc1[tid - EMAX] = mm;
                cone1[tid - EMAX] = (!mm) && (best >= IOU_THRESH);
            }
            __syncthreads();
        }
    }
    __syncthreads();

    // ---- 5) per-batch TP/FN/FP with empty-case rules ----
    if (tid == 0) {
        int n_out = n_out_s, n_tgt = n_tgt_s, tp = tp_sh;
        int tpb, fnb, fpb;
        if (n_tgt == 0)      { tpb = 0;  fnb = n_out;      fpb = 0; }
        else if (n_out == 0) { tpb = 0;  fnb = 0;          fpb = n_tgt; }
        else                 { tpb = tp; fnb = n_tgt - tp; fpb = n_out - tp; }
        atomicAdd(&counters[0], tpb);
        atomicAdd(&counters[1], fnb);
        atomicAdd(&counters[2], fpb);
    }
}

__global__ void zero_counters(int* c) {
    if (threadIdx.x < 3) c[threadIdx.x] = 0;
}

__global__ void finalize_kernel(const int* __restrict__ c, float* __restrict__ out) {
    float TP = (float)c[0], FN = (float)c[1], FP = (float)c[2];
    float rd = TP + FN;
    float recall = (rd == 0.0f) ? 0.0f : TP / fmaxf(rd, 1.0f);
    float pd = TP + FP;
    float precision = (pd == 0.0f) ? 0.0f : TP / fmaxf(pd, 1.0f);
    float s = precision + recall;
    float f1 = (s == 0.0f) ? 0.0f : 2.0f * precision * recall / fmaxf(s, 1e-30f);
    out[0] = recall; out[1] = precision; out[2] = f1;
}

extern "C" void kernel_launch(void* const* d_in, const int* in_sizes, int n_in,
                              void* d_out, int out_size, void* d_ws, size_t ws_size,
                              hipStream_t stream) {
    const float* outp = (const float*)d_in[0];
    const float* tgtp = (const float*)d_in[1];
    float* res = (float*)d_out;
    int* counters = (int*)d_ws;

    zero_counters<<<1, 64, 0, stream>>>(counters);
    event_f1_kernel<<<NBATCH, NTHREADS, 0, stream>>>(outp, tgtp, counters);
    finalize_kernel<<<1, 1, 0, stream>>>(counters, res);
}

// Round 4
// 63.006 us; speedup vs baseline: 3.2566x; 1.5199x over previous
//
#include <hip/hip_runtime.h>

typedef unsigned long long ull;

#define L_LEN 61440
#define NBATCH 512
#define EMAX 128
#define RUNBUF 128          // structurally <=120 output runs (256-block granularity), <=60 target
#define NWORDS 960          // L_LEN / 64
#define NPADW 1080          // padded: w -> w + (w>>3)
#define PADW(w) ((w) + ((w) >> 3))
#define NTHREADS 512
#define IOU_THRESH 0.2f
#define LEN_THRESH 128
#define PADPK 0xF000F000u   // s=61440, e=61440 packed

__device__ __forceinline__ unsigned int mask16_ge(float4 a, float4 b, float4 c, float4 d, float thr) {
    unsigned int m = 0;
    m |= (a.x >= thr) ? 0x0001u : 0u; m |= (a.y >= thr) ? 0x0002u : 0u;
    m |= (a.z >= thr) ? 0x0004u : 0u; m |= (a.w >= thr) ? 0x0008u : 0u;
    m |= (b.x >= thr) ? 0x0010u : 0u; m |= (b.y >= thr) ? 0x0020u : 0u;
    m |= (b.z >= thr) ? 0x0040u : 0u; m |= (b.w >= thr) ? 0x0080u : 0u;
    m |= (c.x >= thr) ? 0x0100u : 0u; m |= (c.y >= thr) ? 0x0200u : 0u;
    m |= (c.z >= thr) ? 0x0400u : 0u; m |= (c.w >= thr) ? 0x0800u : 0u;
    m |= (d.x >= thr) ? 0x1000u : 0u; m |= (d.y >= thr) ? 0x2000u : 0u;
    m |= (d.z >= thr) ? 0x4000u : 0u; m |= (d.w >= thr) ? 0x8000u : 0u;
    return m;
}

__device__ __forceinline__ unsigned int mask16_ne0(float4 a, float4 b, float4 c, float4 d) {
    unsigned int m = 0;
    m |= (a.x != 0.0f) ? 0x0001u : 0u; m |= (a.y != 0.0f) ? 0x0002u : 0u;
    m |= (a.z != 0.0f) ? 0x0004u : 0u; m |= (a.w != 0.0f) ? 0x0008u : 0u;
    m |= (b.x != 0.0f) ? 0x0010u : 0u; m |= (b.y != 0.0f) ? 0x0020u : 0u;
    m |= (b.z != 0.0f) ? 0x0040u : 0u; m |= (b.w != 0.0f) ? 0x0080u : 0u;
    m |= (c.x != 0.0f) ? 0x0100u : 0u; m |= (c.y != 0.0f) ? 0x0200u : 0u;
    m |= (c.z != 0.0f) ? 0x0400u : 0u; m |= (c.w != 0.0f) ? 0x0800u : 0u;
    m |= (d.x != 0.0f) ? 0x1000u : 0u; m |= (d.y != 0.0f) ? 0x2000u : 0u;
    m |= (d.z != 0.0f) ? 0x4000u : 0u; m |= (d.w != 0.0f) ? 0x8000u : 0u;
    return m;
}

__device__ __forceinline__ float iou_pk(unsigned int pk, int ms, int me, int ml) {
    int s = (int)(pk & 0xffffu), e = (int)(pk >> 16);
    int lo = me < e ? me : e;
    int hi = ms > s ? ms : s;
    int inter = lo - hi; if (inter < 0) inter = 0;
    int den = ml + (e - s) - inter; if (den < 1) den = 1;
    return (float)inter / (float)den;
}

__global__ __launch_bounds__(NTHREADS) void event_f1_kernel(
        const float* __restrict__ outp, const float* __restrict__ tgtp,
        int* __restrict__ counters) {
    __shared__ ull bm[2][NPADW];                       // padded bitmask layout
    __shared__ int runs_s[2][RUNBUF], runs_e[2][RUNBUF];
    __shared__ int wtot_s[8], wtot_e[8];
    __shared__ __align__(16) unsigned int pse_o[EMAX], pse_t[EMAX];
    __shared__ int idxr[EMAX], idxc[EMAX];
    __shared__ __align__(16) unsigned int rowfl[EMAX], colfl[EMAX];
    __shared__ int n_out_s, n_tgt_s, ftot0, tp_sh;

    const int tid = threadIdx.x;
    const int lane = tid & 63;
    const int wid = tid >> 6;
    const int row = blockIdx.x;

    const float* op = outp + (size_t)row * L_LEN;
    const float* tg = tgtp + (size_t)row * L_LEN;

    if (tid == 0) tp_sh = 0;

    // ---- 1) build both bitmasks (padded ushort layout) ----
    unsigned short* bmo16 = (unsigned short*)bm[0];
    unsigned short* bmt16 = (unsigned short*)bm[1];
    #pragma unroll 2
    for (int it = 0; it < 7; ++it) {
        const float4* po = (const float4*)(op + it * 8192 + tid * 16);
        const float4* pt = (const float4*)(tg + it * 8192 + tid * 16);
        float4 a0 = po[0], a1 = po[1], a2 = po[2], a3 = po[3];
        float4 b0 = pt[0], b1 = pt[1], b2 = pt[2], b3 = pt[3];
        unsigned int mo = mask16_ge(a0, a1, a2, a3, 0.5f);
        unsigned int mt = mask16_ne0(b0, b1, b2, b3);
        unsigned int u = it * 512 + tid;
        unsigned int pu = u + ((u >> 5) << 2);
        bmo16[pu] = (unsigned short)mo;
        bmt16[pu] = (unsigned short)mt;
    }
    if (tid < 256) {  // tail: elements 57344..61439
        const float4* po = (const float4*)(op + 57344 + tid * 16);
        const float4* pt = (const float4*)(tg + 57344 + tid * 16);
        float4 a0 = po[0], a1 = po[1], a2 = po[2], a3 = po[3];
        float4 b0 = pt[0], b1 = pt[1], b2 = pt[2], b3 = pt[3];
        unsigned int mo = mask16_ge(a0, a1, a2, a3, 0.5f);
        unsigned int mt = mask16_ne0(b0, b1, b2, b3);
        unsigned int u = 3584 + tid;
        unsigned int pu = u + ((u >> 5) << 2);
        bmo16[pu] = (unsigned short)mo;
        bmt16[pu] = (unsigned short)mt;
    }
    __syncthreads();

    // ---- 2) run extraction: threads 0-255 -> output, 256-511 -> target ----
    const int group = tid >> 8;
    const int gtid = tid & 255;
    const ull* bmp = bm[group];
    const int w0 = gtid * 4;
    const bool act = (gtid < 240);

    ull swm0 = 0, swm1 = 0, swm2 = 0, swm3 = 0;
    ull ewm0 = 0, ewm1 = 0, ewm2 = 0, ewm3 = 0;
    int cs = 0, ce = 0;
    if (act) {
        ull wm1 = (w0 > 0) ? bmp[PADW(w0 - 1)] : 0ull;
        int p0 = PADW(w0);
        ull a = bmp[p0], b = bmp[p0 + 1], c = bmp[p0 + 2], d = bmp[p0 + 3];
        ull wp4 = (w0 + 4 < NWORDS) ? bmp[PADW(w0 + 4)] : 0ull;
        swm0 = a & ~((a << 1) | (wm1 >> 63)); ewm0 = a & ~((a >> 1) | (b << 63));
        swm1 = b & ~((b << 1) | (a >> 63));   ewm1 = b & ~((b >> 1) | (c << 63));
        swm2 = c & ~((c << 1) | (b >> 63));   ewm2 = c & ~((c >> 1) | (d << 63));
        swm3 = d & ~((d << 1) | (c >> 63));   ewm3 = d & ~((d >> 1) | (wp4 << 63));
        cs = __popcll(swm0) + __popcll(swm1) + __popcll(swm2) + __popcll(swm3);
        ce = __popcll(ewm0) + __popcll(ewm1) + __popcll(ewm2) + __popcll(ewm3);
    }
    // wave inclusive scan
    int incl_s = cs, incl_e = ce;
    #pragma unroll
    for (int d = 1; d < 64; d <<= 1) {
        int us = __shfl_up(incl_s, d, 64);
        int ue = __shfl_up(incl_e, d, 64);
        if (lane >= d) { incl_s += us; incl_e += ue; }
    }
    if (lane == 63) { wtot_s[wid] = incl_s; wtot_e[wid] = incl_e; }
    __syncthreads();
    int off_s = incl_s - cs, off_e = incl_e - ce;
    for (int wv = (group << 2); wv < wid; ++wv) { off_s += wtot_s[wv]; off_e += wtot_e[wv]; }

    if (act) {
        ull m; int base;
        m = swm0; base = w0 * 64;
        while (m) { int z = __builtin_ctzll(m); if (off_s < RUNBUF) runs_s[group][off_s] = base + z; ++off_s; m &= m - 1; }
        m = swm1; base += 64;
        while (m) { int z = __builtin_ctzll(m); if (off_s < RUNBUF) runs_s[group][off_s] = base + z; ++off_s; m &= m - 1; }
        m = swm2; base += 64;
        while (m) { int z = __builtin_ctzll(m); if (off_s < RUNBUF) runs_s[group][off_s] = base + z; ++off_s; m &= m - 1; }
        m = swm3; base += 64;
        while (m) { int z = __builtin_ctzll(m); if (off_s < RUNBUF) runs_s[group][off_s] = base + z; ++off_s; m &= m - 1; }
        m = ewm0; base = w0 * 64;
        while (m) { int z = __builtin_ctzll(m); if (off_e < RUNBUF) runs_e[group][off_e] = base + z + 1; ++off_e; m &= m - 1; }
        m = ewm1; base += 64;
        while (m) { int z = __builtin_ctzll(m); if (off_e < RUNBUF) runs_e[group][off_e] = base + z + 1; ++off_e; m &= m - 1; }
        m = ewm2; base += 64;
        while (m) { int z = __builtin_ctzll(m); if (off_e < RUNBUF) runs_e[group][off_e] = base + z + 1; ++off_e; m &= m - 1; }
        m = ewm3; base += 64;
        while (m) { int z = __builtin_ctzll(m); if (off_e < RUNBUF) runs_e[group][off_e] = base + z + 1; ++off_e; m &= m - 1; }
    }
    __syncthreads();

    const int nro = wtot_s[0] + wtot_s[1] + wtot_s[2] + wtot_s[3];
    const int nrt = wtot_s[4] + wtot_s[5] + wtot_s[6] + wtot_s[7];

    // ---- 3) filter output runs (parallel scan, threads 0-127); copy target (128-255) ----
    int keep = 0, fs = 0, fe = 0, fincl = 0;
    if (tid < 128) {
        int lim = nro < RUNBUF ? nro : RUNBUF;
        if (tid < lim) { fs = runs_s[0][tid]; fe = runs_e[0][tid]; keep = (fe - fs) >= LEN_THRESH ? 1 : 0; }
        fincl = keep;
        #pragma unroll
        for (int d = 1; d < 64; d <<= 1) {
            int u = __shfl_up(fincl, d, 64);
            if (lane >= d) fincl += u;
        }
        if (tid == 63) ftot0 = fincl;
    } else if (tid < 256) {
        int k = tid - 128;
        int mc = nrt < EMAX ? nrt : EMAX;
        pse_t[k] = (k < mc) ? ((unsigned)runs_s[1][k] | ((unsigned)runs_e[1][k] << 16)) : PADPK;
        if (k == 0) n_tgt_s = nrt;
    }
    __syncthreads();
    if (tid < 128) {
        int off = fincl - keep + (tid >= 64 ? ftot0 : 0);
        if (keep && off < EMAX) pse_o[off] = (unsigned)fs | ((unsigned)fe << 16);
        if (tid == 127) n_out_s = ftot0 + fincl;
    }
    __syncthreads();
    {
        int mcl = n_out_s < EMAX ? n_out_s : EMAX;
        if (tid < 128 && tid >= mcl) pse_o[tid] = PADPK;
    }
    __syncthreads();

    // ---- 4) matching (threads 0-255; rows 0-127, cols 128-255) ----
    int ntc = n_tgt_s < EMAX ? n_tgt_s : EMAX;
    int noc = n_out_s < EMAX ? n_out_s : EMAX;
    const int nt4 = (ntc + 3) & ~3;
    const int no4 = (noc + 3) & ~3;

    unsigned mypk = PADPK;
    if (tid < 128) mypk = pse_o[tid];
    else if (tid < 256) mypk = pse_t[tid - 128];
    const int my_s = (int)(mypk & 0xffffu);
    const int my_e = (int)(mypk >> 16);
    const int my_len = my_e - my_s;

    // ---- pass 0 ----
    float best = -2.0f; int bi = 0;
    if (tid < 128) {
        for (int j = 0; j < nt4; j += 4) {
            uint4 pk = *(const uint4*)&pse_t[j];
            float v0 = iou_pk(pk.x, my_s, my_e, my_len);
            float v1 = iou_pk(pk.y, my_s, my_e, my_len);
            float v2 = iou_pk(pk.z, my_s, my_e, my_len);
            float v3 = iou_pk(pk.w, my_s, my_e, my_len);
            if (v0 > best) { best = v0; bi = j; }
            if (v1 > best) { best = v1; bi = j + 1; }
            if (v2 > best) { best = v2; bi = j + 2; }
            if (v3 > best) { best = v3; bi = j + 3; }
        }
        idxr[tid] = bi;
    } else if (tid < 256) {
        for (int i = 0; i < no4; i += 4) {
            uint4 pk = *(const uint4*)&pse_o[i];
            float v0 = iou_pk(pk.x, my_s, my_e, my_len);
            float v1 = iou_pk(pk.y, my_s, my_e, my_len);
            float v2 = iou_pk(pk.z, my_s, my_e, my_len);
            float v3 = iou_pk(pk.w, my_s, my_e, my_len);
            if (v0 > best) { best = v0; bi = i; }
            if (v1 > best) { best = v1; bi = i + 1; }
            if (v2 > best) { best = v2; bi = i + 2; }
            if (v3 > best) { best = v3; bi = i + 3; }
        }
        idxc[tid - 128] = bi;
    }
    __syncthreads();

    bool mm = false;
    if (tid < 128) mm = (idxc[bi] == tid) && (best >= IOU_THRESH);
    else if (tid < 256) mm = (idxr[bi] == tid - 128) && (best >= IOU_THRESH);
    if (tid < 128) {
        ull bb = __ballot(mm);
        if (lane == 0) atomicAdd(&tp_sh, (int)__popcll(bb));
    }
    __syncthreads();

    const int bi0 = bi;
    const bool m0 = mm;
    const bool one0 = (!mm) && (best >= IOU_THRESH);
    if (tid < 128)      rowfl[tid] = (unsigned)bi0 | (one0 ? 0x100u : 0u) | (m0 ? 0x200u : 0u);
    else if (tid < 256) colfl[tid - 128] = (unsigned)bi0 | (one0 ? 0x100u : 0u) | (m0 ? 0x200u : 0u);
    __syncthreads();

    // ---- pass 1 ----
    best = -2.0f; bi = 0;
    if (tid < 128) {
        const int i = tid;
        for (int j = 0; j < nt4; j += 4) {
            uint4 pk = *(const uint4*)&pse_t[j];
            uint4 fl = *(const uint4*)&colfl[j];
            bool om0 = (((j + 0 == bi0) && one0) || ((i == (int)(fl.x & 0xffu)) && (fl.x & 0x100u))) && !m0 && !(fl.x & 0x200u);
            bool om1 = (((j + 1 == bi0) && one0) || ((i == (int)(fl.y & 0xffu)) && (fl.y & 0x100u))) && !m0 && !(fl.y & 0x200u);
            bool om2 = (((j + 2 == bi0) && one0) || ((i == (int)(fl.z & 0xffu)) && (fl.z & 0x100u))) && !m0 && !(fl.z & 0x200u);
            bool om3 = (((j + 3 == bi0) && one0) || ((i == (int)(fl.w & 0xffu)) && (fl.w & 0x100u))) && !m0 && !(fl.w & 0x200u);
            float v0 = om0 ? iou_pk(pk.x, my_s, my_e, my_len) : -1.0f;
            float v1 = om1 ? iou_pk(pk.y, my_s, my_e, my_len) : -1.0f;
            float v2 = om2 ? iou_pk(pk.z, my_s, my_e, my_len) : -1.0f;
            float v3 = om3 ? iou_pk(pk.w, my_s, my_e, my_len) : -1.0f;
            if (v0 > best) { best = v0; bi = j; }
            if (v1 > best) { best = v1; bi = j + 1; }
            if (v2 > best) { best = v2; bi = j + 2; }
            if (v3 > best) { best = v3; bi = j + 3; }
        }
        idxr[tid] = bi;
    } else if (tid < 256) {
        const int j = tid - 128;
        for (int i = 0; i < no4; i += 4) {
            uint4 pk = *(const uint4*)&pse_o[i];
            uint4 fl = *(const uint4*)&rowfl[i];
            bool om0 = (((j == (int)(fl.x & 0xffu)) && (fl.x & 0x100u)) || ((i + 0 == bi0) && one0)) && !(fl.x & 0x200u) && !m0;
            bool om1 = (((j == (int)(fl.y & 0xffu)) && (fl.y & 0x100u)) || ((i + 1 == bi0) && one0)) && !(fl.y & 0x200u) && !m0;
            bool om2 = (((j == (int)(fl.z & 0xffu)) && (fl.z & 0x100u)) || ((i + 2 == bi0) && one0)) && !(fl.z & 0x200u) && !m0;
            bool om3 = (((j == (int)(fl.w & 0xffu)) && (fl.w & 0x100u)) || ((i + 3 == bi0) && one0)) && !(fl.w & 0x200u) && !m0;
            float v0 = om0 ? iou_pk(pk.x, my_s, my_e, my_len) : -1.0f;
            float v1 = om1 ? iou_pk(pk.y, my_s, my_e, my_len) : -1.0f;
            float v2 = om2 ? iou_pk(pk.z, my_s, my_e, my_len) : -1.0f;
            float v3 = om3 ? iou_pk(pk.w, my_s, my_e, my_len) : -1.0f;
            if (v0 > best) { best = v0; bi = i; }
            if (v1 > best) { best = v1; bi = i + 1; }
            if (v2 > best) { best = v2; bi = i + 2; }
            if (v3 > best) { best = v3; bi = i + 3; }
        }
        idxc[tid - 128] = bi;
    }
    __syncthreads();

    mm = false;
    if (tid < 128) mm = (idxc[bi] == tid) && (best >= IOU_THRESH);
    else if (tid < 256) mm = (idxr[bi] == tid - 128) && (best >= IOU_THRESH);
    if (tid < 128) {
        ull bb = __ballot(mm);
        if (lane == 0) atomicAdd(&tp_sh, (int)__popcll(bb));
    }
    __syncthreads();

    // ---- 5) per-batch TP/FN/FP with empty-case rules ----
    if (tid == 0) {
        int n_out = n_out_s, n_tgt = n_tgt_s, tp = tp_sh;
        int tpb, fnb, fpb;
        if (n_tgt == 0)      { tpb = 0;  fnb = n_out;      fpb = 0; }
        else if (n_out == 0) { tpb = 0;  fnb = 0;          fpb = n_tgt; }
        else                 { tpb = tp; fnb = n_tgt - tp; fpb = n_out - tp; }
        atomicAdd(&counters[0], tpb);
        atomicAdd(&counters[1], fnb);
        atomicAdd(&counters[2], fpb);
    }
}

__global__ void zero_counters(int* c) {
    if (threadIdx.x < 3) c[threadIdx.x] = 0;
}

__global__ void finalize_kernel(const int* __restrict__ c, float* __restrict__ out) {
    float TP = (float)c[0], FN = (float)c[1], FP = (float)c[2];
    float rd = TP + FN;
    float recall = (rd == 0.0f) ? 0.0f : TP / fmaxf(rd, 1.0f);
    float pd = TP + FP;
    float precision = (pd == 0.0f) ? 0.0f : TP / fmaxf(pd, 1.0f);
    float s = precision + recall;
    float f1 = (s == 0.0f) ? 0.0f : 2.0f * precision * recall / fmaxf(s, 1e-30f);
    out[0] = recall; out[1] = precision; out[2] = f1;
}

extern "C" void kernel_launch(void* const* d_in, const int* in_sizes, int n_in,
                              void* d_out, int out_size, void* d_ws, size_t ws_size,
                              hipStream_t stream) {
    const float* outp = (const float*)d_in[0];
    const float* tgtp = (const float*)d_in[1];
    float* res = (float*)d_out;
    int* counters = (int*)d_ws;

    zero_counters<<<1, 64, 0, stream>>>(counters);
    event_f1_kernel<<<NBATCH, NTHREADS, 0, stream>>>(outp, tgtp, counters);
    finalize_kernel<<<1, 1, 0, stream>>>(counters, res);
}

// Round 5
// 57.490 us; speedup vs baseline: 3.5690x; 1.0959x over previous
//
#include <hip/hip_runtime.h>

typedef unsigned long long ull;

#define L_LEN 61440
#define NBATCH 512
#define EMAX 128
#define RUNBUF 128          // structurally <=120 output runs (256-block granularity), <=60 target
#define NWORDS 960          // L_LEN / 64
#define NPADW 1080          // padded: w -> w + (w>>3)
#define PADW(w) ((w) + ((w) >> 3))
#define NTHREADS 1024
#define IOU_THRESH 0.2f
#define LEN_THRESH 128
#define PADPK 0xF000F000u   // s=61440, e=61440 packed

__device__ __forceinline__ unsigned int mask16_ge(float4 a, float4 b, float4 c, float4 d, float thr) {
    unsigned int m = 0;
    m |= (a.x >= thr) ? 0x0001u : 0u; m |= (a.y >= thr) ? 0x0002u : 0u;
    m |= (a.z >= thr) ? 0x0004u : 0u; m |= (a.w >= thr) ? 0x0008u : 0u;
    m |= (b.x >= thr) ? 0x0010u : 0u; m |= (b.y >= thr) ? 0x0020u : 0u;
    m |= (b.z >= thr) ? 0x0040u : 0u; m |= (b.w >= thr) ? 0x0080u : 0u;
    m |= (c.x >= thr) ? 0x0100u : 0u; m |= (c.y >= thr) ? 0x0200u : 0u;
    m |= (c.z >= thr) ? 0x0400u : 0u; m |= (c.w >= thr) ? 0x0800u : 0u;
    m |= (d.x >= thr) ? 0x1000u : 0u; m |= (d.y >= thr) ? 0x2000u : 0u;
    m |= (d.z >= thr) ? 0x4000u : 0u; m |= (d.w >= thr) ? 0x8000u : 0u;
    return m;
}

__device__ __forceinline__ unsigned int mask16_ne0(float4 a, float4 b, float4 c, float4 d) {
    unsigned int m = 0;
    m |= (a.x != 0.0f) ? 0x0001u : 0u; m |= (a.y != 0.0f) ? 0x0002u : 0u;
    m |= (a.z != 0.0f) ? 0x0004u : 0u; m |= (a.w != 0.0f) ? 0x0008u : 0u;
    m |= (b.x != 0.0f) ? 0x0010u : 0u; m |= (b.y != 0.0f) ? 0x0020u : 0u;
    m |= (b.z != 0.0f) ? 0x0040u : 0u; m |= (b.w != 0.0f) ? 0x0080u : 0u;
    m |= (c.x != 0.0f) ? 0x0100u : 0u; m |= (c.y != 0.0f) ? 0x0200u : 0u;
    m |= (c.z != 0.0f) ? 0x0400u : 0u; m |= (c.w != 0.0f) ? 0x0800u : 0u;
    m |= (d.x != 0.0f) ? 0x1000u : 0u; m |= (d.y != 0.0f) ? 0x2000u : 0u;
    m |= (d.z != 0.0f) ? 0x4000u : 0u; m |= (d.w != 0.0f) ? 0x8000u : 0u;
    return m;
}

__device__ __forceinline__ float iou_pk(unsigned int pk, int ms, int me, int ml) {
    int s = (int)(pk & 0xffffu), e = (int)(pk >> 16);
    int lo = me < e ? me : e;
    int hi = ms > s ? ms : s;
    int inter = lo - hi; if (inter < 0) inter = 0;
    int den = ml + (e - s) - inter; if (den < 1) den = 1;
    return (float)inter / (float)den;
}

__global__ __launch_bounds__(NTHREADS) void event_f1_kernel(
        const float* __restrict__ outp, const float* __restrict__ tgtp,
        int* __restrict__ per_row) {
    __shared__ ull bm[2][NPADW];                       // padded bitmask layout
    __shared__ int runs_s[2][RUNBUF], runs_e[2][RUNBUF];
    __shared__ int wtot_s[16], wtot_e[16];
    __shared__ __align__(16) unsigned int pse_o[EMAX], pse_t[EMAX];
    __shared__ int idxr[EMAX], idxc[EMAX];
    __shared__ __align__(16) unsigned int rowfl[EMAX], colfl[EMAX];
    __shared__ int n_out_s, n_tgt_s, ftot0, tp_sh;

    const int tid = threadIdx.x;
    const int lane = tid & 63;
    const int wid = tid >> 6;
    const int row = blockIdx.x;

    const float* op = outp + (size_t)row * L_LEN;
    const float* tg = tgtp + (size_t)row * L_LEN;

    if (tid == 0) tp_sh = 0;

    // ---- 1) build both bitmasks (padded ushort layout) ----
    // 1024 threads x 16 elems = 16384/iter; 3 full iters + 768-thread tail.
    unsigned short* bmo16 = (unsigned short*)bm[0];
    unsigned short* bmt16 = (unsigned short*)bm[1];
    #pragma unroll 1
    for (int it = 0; it < 4; ++it) {
        if (it == 3 && tid >= 768) break;
        const float4* po = (const float4*)(op + it * 16384 + tid * 16);
        const float4* pt = (const float4*)(tg + it * 16384 + tid * 16);
        float4 a0 = po[0], a1 = po[1], a2 = po[2], a3 = po[3];
        float4 b0 = pt[0], b1 = pt[1], b2 = pt[2], b3 = pt[3];
        unsigned int mo = mask16_ge(a0, a1, a2, a3, 0.5f);
        unsigned int mt = mask16_ne0(b0, b1, b2, b3);
        unsigned int u = it * 1024 + tid;
        unsigned int pu = u + ((u >> 5) << 2);
        bmo16[pu] = (unsigned short)mo;
        bmt16[pu] = (unsigned short)mt;
    }
    __syncthreads();

    // ---- 2) run extraction: threads 0-255 -> output, 256-511 -> target ----
    const int group = tid >> 8;            // 0..3; only 0,1 active
    const int g = group & 1;
    const int gtid = tid & 255;
    const ull* bmp = bm[g];
    const int w0 = gtid * 4;
    const bool act = (tid < 512) && (gtid < 240);

    ull swm0 = 0, swm1 = 0, swm2 = 0, swm3 = 0;
    ull ewm0 = 0, ewm1 = 0, ewm2 = 0, ewm3 = 0;
    int cs = 0, ce = 0;
    if (act) {
        ull wm1 = (w0 > 0) ? bmp[PADW(w0 - 1)] : 0ull;
        int p0 = PADW(w0);
        ull a = bmp[p0], b = bmp[p0 + 1], c = bmp[p0 + 2], d = bmp[p0 + 3];
        ull wp4 = (w0 + 4 < NWORDS) ? bmp[PADW(w0 + 4)] : 0ull;
        swm0 = a & ~((a << 1) | (wm1 >> 63)); ewm0 = a & ~((a >> 1) | (b << 63));
        swm1 = b & ~((b << 1) | (a >> 63));   ewm1 = b & ~((b >> 1) | (c << 63));
        swm2 = c & ~((c << 1) | (b >> 63));   ewm2 = c & ~((c >> 1) | (d << 63));
        swm3 = d & ~((d << 1) | (c >> 63));   ewm3 = d & ~((d >> 1) | (wp4 << 63));
        cs = __popcll(swm0) + __popcll(swm1) + __popcll(swm2) + __popcll(swm3);
        ce = __popcll(ewm0) + __popcll(ewm1) + __popcll(ewm2) + __popcll(ewm3);
    }
    // wave inclusive scan
    int incl_s = cs, incl_e = ce;
    #pragma unroll
    for (int d = 1; d < 64; d <<= 1) {
        int us = __shfl_up(incl_s, d, 64);
        int ue = __shfl_up(incl_e, d, 64);
        if (lane >= d) { incl_s += us; incl_e += ue; }
    }
    if (lane == 63) { wtot_s[wid] = incl_s; wtot_e[wid] = incl_e; }
    __syncthreads();
    int off_s = incl_s - cs, off_e = incl_e - ce;
    if (act) {
        for (int wv = (g << 2); wv < wid; ++wv) { off_s += wtot_s[wv]; off_e += wtot_e[wv]; }
        ull m; int base;
        m = swm0; base = w0 * 64;
        while (m) { int z = __builtin_ctzll(m); if (off_s < RUNBUF) runs_s[g][off_s] = base + z; ++off_s; m &= m - 1; }
        m = swm1; base += 64;
        while (m) { int z = __builtin_ctzll(m); if (off_s < RUNBUF) runs_s[g][off_s] = base + z; ++off_s; m &= m - 1; }
        m = swm2; base += 64;
        while (m) { int z = __builtin_ctzll(m); if (off_s < RUNBUF) runs_s[g][off_s] = base + z; ++off_s; m &= m - 1; }
        m = swm3; base += 64;
        while (m) { int z = __builtin_ctzll(m); if (off_s < RUNBUF) runs_s[g][off_s] = base + z; ++off_s; m &= m - 1; }
        m = ewm0; base = w0 * 64;
        while (m) { int z = __builtin_ctzll(m); if (off_e < RUNBUF) runs_e[g][off_e] = base + z + 1; ++off_e; m &= m - 1; }
        m = ewm1; base += 64;
        while (m) { int z = __builtin_ctzll(m); if (off_e < RUNBUF) runs_e[g][off_e] = base + z + 1; ++off_e; m &= m - 1; }
        m = ewm2; base += 64;
        while (m) { int z = __builtin_ctzll(m); if (off_e < RUNBUF) runs_e[g][off_e] = base + z + 1; ++off_e; m &= m - 1; }
        m = ewm3; base += 64;
        while (m) { int z = __builtin_ctzll(m); if (off_e < RUNBUF) runs_e[g][off_e] = base + z + 1; ++off_e; m &= m - 1; }
    }
    __syncthreads();

    const int nro = wtot_s[0] + wtot_s[1] + wtot_s[2] + wtot_s[3];
    const int nrt = wtot_s[4] + wtot_s[5] + wtot_s[6] + wtot_s[7];

    // ---- 3) filter output runs (parallel scan, threads 0-127); copy target (128-255) ----
    int keep = 0, fs = 0, fe = 0, fincl = 0;
    if (tid < 128) {
        int lim = nro < RUNBUF ? nro : RUNBUF;
        if (tid < lim) { fs = runs_s[0][tid]; fe = runs_e[0][tid]; keep = (fe - fs) >= LEN_THRESH ? 1 : 0; }
        fincl = keep;
        #pragma unroll
        for (int d = 1; d < 64; d <<= 1) {
            int u = __shfl_up(fincl, d, 64);
            if (lane >= d) fincl += u;
        }
        if (tid == 63) ftot0 = fincl;
    } else if (tid < 256) {
        int k = tid - 128;
        int mc = nrt < EMAX ? nrt : EMAX;
        pse_t[k] = (k < mc) ? ((unsigned)runs_s[1][k] | ((unsigned)runs_e[1][k] << 16)) : PADPK;
        if (k == 0) n_tgt_s = nrt;
    }
    __syncthreads();
    if (tid < 128) {
        int off = fincl - keep + (tid >= 64 ? ftot0 : 0);
        if (keep && off < EMAX) pse_o[off] = (unsigned)fs | ((unsigned)fe << 16);
        if (tid == 127) n_out_s = ftot0 + fincl;
    }
    __syncthreads();
    {
        int mcl = n_out_s < EMAX ? n_out_s : EMAX;
        if (tid < 128 && tid >= mcl) pse_o[tid] = PADPK;
    }
    __syncthreads();

    // ---- 4) matching (threads 0-255; rows 0-127, cols 128-255) ----
    int ntc = n_tgt_s < EMAX ? n_tgt_s : EMAX;
    int noc = n_out_s < EMAX ? n_out_s : EMAX;
    const int nt4 = (ntc + 3) & ~3;
    const int no4 = (noc + 3) & ~3;

    unsigned mypk = PADPK;
    if (tid < 128) mypk = pse_o[tid];
    else if (tid < 256) mypk = pse_t[tid - 128];
    const int my_s = (int)(mypk & 0xffffu);
    const int my_e = (int)(mypk >> 16);
    const int my_len = my_e - my_s;

    // ---- pass 0 ----
    float best = -2.0f; int bi = 0;
    if (tid < 128) {
        for (int j = 0; j < nt4; j += 4) {
            uint4 pk = *(const uint4*)&pse_t[j];
            float v0 = iou_pk(pk.x, my_s, my_e, my_len);
            float v1 = iou_pk(pk.y, my_s, my_e, my_len);
            float v2 = iou_pk(pk.z, my_s, my_e, my_len);
            float v3 = iou_pk(pk.w, my_s, my_e, my_len);
            if (v0 > best) { best = v0; bi = j; }
            if (v1 > best) { best = v1; bi = j + 1; }
            if (v2 > best) { best = v2; bi = j + 2; }
            if (v3 > best) { best = v3; bi = j + 3; }
        }
        idxr[tid] = bi;
    } else if (tid < 256) {
        for (int i = 0; i < no4; i += 4) {
            uint4 pk = *(const uint4*)&pse_o[i];
            float v0 = iou_pk(pk.x, my_s, my_e, my_len);
            float v1 = iou_pk(pk.y, my_s, my_e, my_len);
            float v2 = iou_pk(pk.z, my_s, my_e, my_len);
            float v3 = iou_pk(pk.w, my_s, my_e, my_len);
            if (v0 > best) { best = v0; bi = i; }
            if (v1 > best) { best = v1; bi = i + 1; }
            if (v2 > best) { best = v2; bi = i + 2; }
            if (v3 > best) { best = v3; bi = i + 3; }
        }
        idxc[tid - 128] = bi;
    }
    __syncthreads();

    bool mm = false;
    if (tid < 128) mm = (idxc[bi] == tid) && (best >= IOU_THRESH);
    else if (tid < 256) mm = (idxr[bi] == tid - 128) && (best >= IOU_THRESH);
    if (tid < 128) {
        ull bb = __ballot(mm);
        if (lane == 0) atomicAdd(&tp_sh, (int)__popcll(bb));
    }
    __syncthreads();

    const int bi0 = bi;
    const bool m0 = mm;
    const bool one0 = (!mm) && (best >= IOU_THRESH);
    if (tid < 128)      rowfl[tid] = (unsigned)bi0 | (one0 ? 0x100u : 0u) | (m0 ? 0x200u : 0u);
    else if (tid < 256) colfl[tid - 128] = (unsigned)bi0 | (one0 ? 0x100u : 0u) | (m0 ? 0x200u : 0u);
    __syncthreads();

    // ---- pass 1 ----
    best = -2.0f; bi = 0;
    if (tid < 128) {
        const int i = tid;
        for (int j = 0; j < nt4; j += 4) {
            uint4 pk = *(const uint4*)&pse_t[j];
            uint4 fl = *(const uint4*)&colfl[j];
            bool om0 = (((j + 0 == bi0) && one0) || ((i == (int)(fl.x & 0xffu)) && (fl.x & 0x100u))) && !m0 && !(fl.x & 0x200u);
            bool om1 = (((j + 1 == bi0) && one0) || ((i == (int)(fl.y & 0xffu)) && (fl.y & 0x100u))) && !m0 && !(fl.y & 0x200u);
            bool om2 = (((j + 2 == bi0) && one0) || ((i == (int)(fl.z & 0xffu)) && (fl.z & 0x100u))) && !m0 && !(fl.z & 0x200u);
            bool om3 = (((j + 3 == bi0) && one0) || ((i == (int)(fl.w & 0xffu)) && (fl.w & 0x100u))) && !m0 && !(fl.w & 0x200u);
            float v0 = om0 ? iou_pk(pk.x, my_s, my_e, my_len) : -1.0f;
            float v1 = om1 ? iou_pk(pk.y, my_s, my_e, my_len) : -1.0f;
            float v2 = om2 ? iou_pk(pk.z, my_s, my_e, my_len) : -1.0f;
            float v3 = om3 ? iou_pk(pk.w, my_s, my_e, my_len) : -1.0f;
            if (v0 > best) { best = v0; bi = j; }
            if (v1 > best) { best = v1; bi = j + 1; }
            if (v2 > best) { best = v2; bi = j + 2; }
            if (v3 > best) { best = v3; bi = j + 3; }
        }
        idxr[tid] = bi;
    } else if (tid < 256) {
        const int j = tid - 128;
        for (int i = 0; i < no4; i += 4) {
            uint4 pk = *(const uint4*)&pse_o[i];
            uint4 fl = *(const uint4*)&rowfl[i];
            bool om0 = (((j == (int)(fl.x & 0xffu)) && (fl.x & 0x100u)) || ((i + 0 == bi0) && one0)) && !(fl.x & 0x200u) && !m0;
            bool om1 = (((j == (int)(fl.y & 0xffu)) && (fl.y & 0x100u)) || ((i + 1 == bi0) && one0)) && !(fl.y & 0x200u) && !m0;
            bool om2 = (((j == (int)(fl.z & 0xffu)) && (fl.z & 0x100u)) || ((i + 2 == bi0) && one0)) && !(fl.z & 0x200u) && !m0;
            bool om3 = (((j == (int)(fl.w & 0xffu)) && (fl.w & 0x100u)) || ((i + 3 == bi0) && one0)) && !(fl.w & 0x200u) && !m0;
            float v0 = om0 ? iou_pk(pk.x, my_s, my_e, my_len) : -1.0f;
            float v1 = om1 ? iou_pk(pk.y, my_s, my_e, my_len) : -1.0f;
            float v2 = om2 ? iou_pk(pk.z, my_s, my_e, my_len) : -1.0f;
            float v3 = om3 ? iou_pk(pk.w, my_s, my_e, my_len) : -1.0f;
            if (v0 > best) { best = v0; bi = i; }
            if (v1 > best) { best = v1; bi = i + 1; }
            if (v2 > best) { best = v2; bi = i + 2; }
            if (v3 > best) { best = v3; bi = i + 3; }
        }
        idxc[tid - 128] = bi;
    }
    __syncthreads();

    mm = false;
    if (tid < 128) mm = (idxc[bi] == tid) && (best >= IOU_THRESH);
    else if (tid < 256) mm = (idxr[bi] == tid - 128) && (best >= IOU_THRESH);
    if (tid < 128) {
        ull bb = __ballot(mm);
        if (lane == 0) atomicAdd(&tp_sh, (int)__popcll(bb));
    }
    __syncthreads();

    // ---- 5) per-batch TP/FN/FP with empty-case rules -> per-row slots (no zeroing needed) ----
    if (tid == 0) {
        int n_out = n_out_s, n_tgt = n_tgt_s, tp = tp_sh;
        int tpb, fnb, fpb;
        if (n_tgt == 0)      { tpb = 0;  fnb = n_out;      fpb = 0; }
        else if (n_out == 0) { tpb = 0;  fnb = 0;          fpb = n_tgt; }
        else                 { tpb = tp; fnb = n_tgt - tp; fpb = n_out - tp; }
        per_row[row * 3 + 0] = tpb;
        per_row[row * 3 + 1] = fnb;
        per_row[row * 3 + 2] = fpb;
    }
}

__global__ __launch_bounds__(512) void finalize_kernel(const int* __restrict__ per_row,
                                                       float* __restrict__ out) {
    __shared__ int sm[3][8];
    const int tid = threadIdx.x;
    const int lane = tid & 63;
    const int wid = tid >> 6;
    int tp = per_row[tid * 3 + 0];
    int fn = per_row[tid * 3 + 1];
    int fp = per_row[tid * 3 + 2];
    #pragma unroll
    for (int d = 32; d > 0; d >>= 1) {
        tp += __shfl_down(tp, d, 64);
        fn += __shfl_down(fn, d, 64);
        fp += __shfl_down(fp, d, 64);
    }
    if (lane == 0) { sm[0][wid] = tp; sm[1][wid] = fn; sm[2][wid] = fp; }
    __syncthreads();
    if (tid == 0) {
        int TPi = 0, FNi = 0, FPi = 0;
        #pragma unroll
        for (int w = 0; w < 8; ++w) { TPi += sm[0][w]; FNi += sm[1][w]; FPi += sm[2][w]; }
        float TP = (float)TPi, FN = (float)FNi, FP = (float)FPi;
        float rd = TP + FN;
        float recall = (rd == 0.0f) ? 0.0f : TP / fmaxf(rd, 1.0f);
        float pd = TP + FP;
        float precision = (pd == 0.0f) ? 0.0f : TP / fmaxf(pd, 1.0f);
        float s = precision + recall;
        float f1 = (s == 0.0f) ? 0.0f : 2.0f * precision * recall / fmaxf(s, 1e-30f);
        out[0] = recall; out[1] = precision; out[2] = f1;
    }
}

extern "C" void kernel_launch(void* const* d_in, const int* in_sizes, int n_in,
                              void* d_out, int out_size, void* d_ws, size_t ws_size,
                              hipStream_t stream) {
    const float* outp = (const float*)d_in[0];
    const float* tgtp = (const float*)d_in[1];
    float* res = (float*)d_out;
    int* per_row = (int*)d_ws;

    event_f1_kernel<<<NBATCH, NTHREADS, 0, stream>>>(outp, tgtp, per_row);
    finalize_kernel<<<1, 512, 0, stream>>>(per_row, res);
}